// Round 5
// baseline (465.336 us; speedup 1.0000x reference)
//
#include <hip/hip_runtime.h>
#include <hip/hip_bf16.h>
#include <hip/hip_fp16.h>

#define NN 100000
#define EE 1600000
#define FF 128
#define HH 128
#define CC 8
#define NB ((NN + 63) / 64)  // buckets of 64 nodes

typedef _Float16 half8 __attribute__((ext_vector_type(8)));
typedef float f32x4 __attribute__((ext_vector_type(4)));

// ---------------- degree ----------------
__global__ __launch_bounds__(256) void k_count(const int* __restrict__ dst,
                                               int* __restrict__ cnt, int e) {
  int i = blockIdx.x * 256 + threadIdx.x;
  if (i < e) atomicAdd(&cnt[dst[i]], 1);
}

// ---------------- scan (exclusive) for CSR row_ptr, fused dinv --------------
__global__ __launch_bounds__(1024) void k_scan1(const int* __restrict__ cnt,
                                                int* __restrict__ rowptr,
                                                int* __restrict__ bsum,
                                                float* __restrict__ dinv, int n) {
  __shared__ int sh[1024];
  int t = threadIdx.x;
  int i = blockIdx.x * 1024 + t;
  int v = (i < n) ? cnt[i] : 0;
  if (i < n) dinv[i] = rsqrtf((float)v + 1.0f);  // +1 self loop
  sh[t] = v;
  __syncthreads();
  for (int offs = 1; offs < 1024; offs <<= 1) {
    int add = (t >= offs) ? sh[t - offs] : 0;
    __syncthreads();
    sh[t] += add;
    __syncthreads();
  }
  if (i < n) rowptr[i] = sh[t] - v;  // exclusive
  if (t == 1023) bsum[blockIdx.x] = sh[1023];
}

__global__ __launch_bounds__(128) void k_scan2(int* __restrict__ bsum, int nb) {
  __shared__ int sh[128];
  int t = threadIdx.x;
  int v = (t < nb) ? bsum[t] : 0;
  sh[t] = v;
  __syncthreads();
  for (int offs = 1; offs < 128; offs <<= 1) {
    int add = (t >= offs) ? sh[t - offs] : 0;
    __syncthreads();
    sh[t] += add;
    __syncthreads();
  }
  if (t < nb) bsum[t] = sh[t] - v;  // exclusive
}

__global__ __launch_bounds__(1024) void k_scan3(int* __restrict__ rowptr,
                                                const int* __restrict__ bsum,
                                                int n, int e) {
  int i = blockIdx.x * 1024 + threadIdx.x;
  if (i < n) rowptr[i] += bsum[blockIdx.x];
  if (i == 0) rowptr[n] = e;
}

// ---------------- bucket cursor init: bcursor[b] = rowptr[64b] --------------
__global__ __launch_bounds__(256) void k_binit(const int* __restrict__ rowptr,
                                               int* __restrict__ bcursor) {
  int b = blockIdx.x * 256 + threadIdx.x;
  if (b < NB) bcursor[b] = rowptr[b * 64];
}

// ---------------- Phase A: partition edges into dst-buckets ----------------
// stage[pos] = src | ((dst&63) << 17)   (src < 2^17, 4 B/edge)
__global__ __launch_bounds__(256) void k_bucketA(const int* __restrict__ src,
                                                 const int* __restrict__ dst,
                                                 int* __restrict__ bcursor,
                                                 unsigned int* __restrict__ stage,
                                                 int e) {
  int i = blockIdx.x * 256 + threadIdx.x;
  if (i >= e) return;
  int d = dst[i];
  int s = src[i];
  int pos = atomicAdd(&bcursor[d >> 6], 1);
  stage[pos] = (unsigned int)s | ((unsigned int)(d & 63) << 17);
}

// ---------------- Phase B: one block per bucket, LDS cursors ----------------
__global__ __launch_bounds__(256) void k_bucketB(const unsigned int* __restrict__ stage,
                                                 const int* __restrict__ rowptr,
                                                 int* __restrict__ col) {
  __shared__ int lcur[64];
  int b = blockIdx.x;
  int n0 = b * 64;
  int t = threadIdx.x;
  if (t < 64) {
    int node = n0 + t;
    lcur[t] = (node < NN) ? rowptr[node] : 0;
  }
  __syncthreads();
  int base = rowptr[n0];
  int end = rowptr[(n0 + 64 < NN) ? n0 + 64 : NN];
  for (int j = base + t; j < end; j += 256) {
    unsigned int v = stage[j];
    int s = (int)(v & 0x1FFFFu);
    int dloc = (int)(v >> 17);
    int pos = atomicAdd(&lcur[dloc], 1);
    col[pos] = s;
  }
}

// ---------------- GEMM1 (MFMA fp16): h = x @ W1, fp16 out -------------------
__global__ __launch_bounds__(256) void k_gemm1(const float* __restrict__ x,
                                               const float* __restrict__ W,
                                               __half* __restrict__ h, int n) {
  __shared__ _Float16 Wl[128 * 128];  // [c][k] swizzled
  int t = threadIdx.x;
  {
    int c = t & 127;
    int kg0 = t >> 7;  // 0..1
    for (int kg = kg0; kg < 16; kg += 2) {
      _Float16 tmp[8];
#pragma unroll
      for (int j = 0; j < 8; ++j)
        tmp[j] = (_Float16)W[(size_t)(kg * 8 + j) * 128 + c];
      int byteoff = (c * 256 + kg * 16) ^ ((c & 7) << 4);
      *(half8*)((char*)Wl + byteoff) = *(half8*)tmp;
    }
  }
  __syncthreads();

  int row0 = blockIdx.x * 64;
  int w = t >> 6, l = t & 63;
  int rw = w >> 1, cw = w & 1;
  int lr = l & 15, g = l >> 4;

  f32x4 acc[2][4];
#pragma unroll
  for (int ar = 0; ar < 2; ++ar)
#pragma unroll
    for (int bt = 0; bt < 4; ++bt)
#pragma unroll
      for (int r = 0; r < 4; ++r) acc[ar][bt][r] = 0.f;

  for (int kt = 0; kt < 4; ++kt) {
    half8 a[2];
#pragma unroll
    for (int ar = 0; ar < 2; ++ar) {
      int row = row0 + rw * 32 + ar * 16 + lr;
      if (row < n) {
        const float* p = &x[(size_t)row * 128 + kt * 32 + g * 8];
        float4 v0 = *(const float4*)p;
        float4 v1 = *(const float4*)(p + 4);
        a[ar][0] = (_Float16)v0.x; a[ar][1] = (_Float16)v0.y;
        a[ar][2] = (_Float16)v0.z; a[ar][3] = (_Float16)v0.w;
        a[ar][4] = (_Float16)v1.x; a[ar][5] = (_Float16)v1.y;
        a[ar][6] = (_Float16)v1.z; a[ar][7] = (_Float16)v1.w;
      } else {
#pragma unroll
        for (int j = 0; j < 8; ++j) a[ar][j] = (_Float16)0.f;
      }
    }
#pragma unroll
    for (int bt = 0; bt < 4; ++bt) {
      int c = cw * 64 + bt * 16 + lr;
      int byteoff = (c * 256 + kt * 64 + g * 16) ^ ((c & 7) << 4);
      half8 bb = *(const half8*)((const char*)Wl + byteoff);
      acc[0][bt] = __builtin_amdgcn_mfma_f32_16x16x32_f16(a[0], bb, acc[0][bt], 0, 0, 0);
      acc[1][bt] = __builtin_amdgcn_mfma_f32_16x16x32_f16(a[1], bb, acc[1][bt], 0, 0, 0);
    }
  }

#pragma unroll
  for (int ar = 0; ar < 2; ++ar)
#pragma unroll
    for (int bt = 0; bt < 4; ++bt)
#pragma unroll
      for (int r = 0; r < 4; ++r) {
        int row = row0 + rw * 32 + ar * 16 + g * 4 + r;
        int c = cw * 64 + bt * 16 + lr;
        if (row < n) h[(size_t)row * 128 + c] = __float2half(acc[ar][bt][r]);
      }
}

// ---------------- Agg1: out = relu(Anorm @ h + b1), wave per node, fp16 ----
__global__ __launch_bounds__(256) void k_agg1(const __half* __restrict__ h,
                                              const int* __restrict__ rowptr,
                                              const int* __restrict__ col,
                                              const float* __restrict__ dinv,
                                              const float* __restrict__ b1,
                                              __half2* __restrict__ out, int n) {
  int wid = threadIdx.x >> 6;
  int lane = threadIdx.x & 63;
  int node = blockIdx.x * 4 + wid;
  if (node >= n) return;
  float dn = dinv[node];
  const __half2* hp = (const __half2*)h;
  float2 acc = make_float2(0.f, 0.f);
  int e0 = rowptr[node], e1 = rowptr[node + 1];
  int e = e0;
  for (; e + 3 < e1; e += 4) {  // 4 gathers in flight
    int s0 = col[e], s1 = col[e + 1], s2 = col[e + 2], s3 = col[e + 3];
    float w0 = dinv[s0] * dn, w1 = dinv[s1] * dn;
    float w2 = dinv[s2] * dn, w3 = dinv[s3] * dn;
    float2 f0 = __half22float2(hp[(size_t)s0 * 64 + lane]);
    float2 f1 = __half22float2(hp[(size_t)s1 * 64 + lane]);
    float2 f2 = __half22float2(hp[(size_t)s2 * 64 + lane]);
    float2 f3 = __half22float2(hp[(size_t)s3 * 64 + lane]);
    acc.x = fmaf(w0, f0.x, acc.x); acc.y = fmaf(w0, f0.y, acc.y);
    acc.x = fmaf(w1, f1.x, acc.x); acc.y = fmaf(w1, f1.y, acc.y);
    acc.x = fmaf(w2, f2.x, acc.x); acc.y = fmaf(w2, f2.y, acc.y);
    acc.x = fmaf(w3, f3.x, acc.x); acc.y = fmaf(w3, f3.y, acc.y);
  }
  for (; e < e1; ++e) {
    int s = col[e];
    float w = dinv[s] * dn;
    float2 f = __half22float2(hp[(size_t)s * 64 + lane]);
    acc.x = fmaf(w, f.x, acc.x);
    acc.y = fmaf(w, f.y, acc.y);
  }
  {  // self loop
    float w = dn * dn;
    float2 f = __half22float2(hp[(size_t)node * 64 + lane]);
    acc.x = fmaf(w, f.x, acc.x);
    acc.y = fmaf(w, f.y, acc.y);
  }
  float2 bb = ((const float2*)b1)[lane];
  acc.x = fmaxf(acc.x + bb.x, 0.f);
  acc.y = fmaxf(acc.y + bb.y, 0.f);
  out[(size_t)node * 64 + lane] = __floats2half2_rn(acc.x, acc.y);
}

// ---------------- GEMM2: h2 = a @ W2 (fp16 in, fp16 out), thread per row ---
__global__ __launch_bounds__(256) void k_gemm2(const __half* __restrict__ a,
                                               const float* __restrict__ W2,
                                               __half* __restrict__ h2, int n) {
  int r = blockIdx.x * 256 + threadIdx.x;
  if (r >= n) return;
  float acc[8];
#pragma unroll
  for (int c = 0; c < 8; ++c) acc[c] = 0.f;
  const __half2* ap = (const __half2*)(a + (size_t)r * 128);
#pragma unroll 8
  for (int k2 = 0; k2 < 64; ++k2) {
    float2 v = __half22float2(ap[k2]);
    int k = k2 * 2;
#pragma unroll
    for (int c = 0; c < 8; ++c) {
      acc[c] = fmaf(v.x, W2[(k + 0) * 8 + c], acc[c]);
      acc[c] = fmaf(v.y, W2[(k + 1) * 8 + c], acc[c]);
    }
  }
  union { __half2 h2v[4]; uint2 u2[2]; } pk;
#pragma unroll
  for (int c = 0; c < 4; ++c)
    pk.h2v[c] = __floats2half2_rn(acc[2 * c], acc[2 * c + 1]);
  *(uint2*)&h2[(size_t)r * 8] = pk.u2[0];
  *(uint2*)&h2[(size_t)r * 8 + 4] = pk.u2[1];
}

// ---------------- Agg2: out = Anorm @ h2 + b2, 8 threads per node ----------
__global__ __launch_bounds__(256) void k_agg2(const __half* __restrict__ h2,
                                              const int* __restrict__ rowptr,
                                              const int* __restrict__ col,
                                              const float* __restrict__ dinv,
                                              const float* __restrict__ b2,
                                              float* __restrict__ out, int n) {
  int gthread = blockIdx.x * 256 + threadIdx.x;
  int node = gthread >> 3, f = gthread & 7;
  if (node >= n) return;
  float dn = dinv[node];
  float acc = 0.f;
  int e0 = rowptr[node], e1 = rowptr[node + 1];
  for (int e = e0; e < e1; ++e) {
    int s = col[e];
    acc = fmaf(dinv[s] * dn, __half2float(h2[(size_t)s * 8 + f]), acc);
  }
  acc = fmaf(dn * dn, __half2float(h2[(size_t)node * 8 + f]), acc);
  out[(size_t)node * 8 + f] = acc + b2[f];
}

extern "C" void kernel_launch(void* const* d_in, const int* in_sizes, int n_in,
                              void* d_out, int out_size, void* d_ws, size_t ws_size,
                              hipStream_t stream) {
  const float* x  = (const float*)d_in[0];
  const int* eidx = (const int*)d_in[1];
  const float* W1 = (const float*)d_in[2];
  const float* b1 = (const float*)d_in[3];
  const float* W2 = (const float*)d_in[4];
  const float* b2 = (const float*)d_in[5];
  float* out = (float*)d_out;
  const int* src = eidx;
  const int* dst = eidx + EE;

  char* ws = (char*)d_ws;
  size_t off = 0;
  auto alloc = [&](size_t bytes) -> char* {
    char* p = ws + off;
    off = (off + bytes + 255) & ~(size_t)255;
    return p;
  };

  int*          cnt     = (int*)         alloc((size_t)NN * 4);
  float*        dinv    = (float*)       alloc((size_t)NN * 4);
  int*          rowptr  = (int*)         alloc((size_t)(NN + 1) * 4);
  int*          bsum    = (int*)         alloc(1024 * 4);
  int*          bcursor = (int*)         alloc((size_t)NB * 4);
  unsigned int* stage   = (unsigned int*)alloc((size_t)EE * 4);
  int*          colbuf  = (int*)         alloc((size_t)EE * 4);
  __half*       h1      = (__half*)      alloc((size_t)NN * HH * 2);
  __half2*      agg1    = (__half2*)     alloc((size_t)NN * HH * 2);
  __half*       h2      = (__half*)h1;  // reuse: h1 dead after agg1

  hipMemsetAsync(cnt, 0, (size_t)NN * 4, stream);

  int nbE = (EE + 255) / 256;
  int nbScan = (NN + 1023) / 1024;

  k_count<<<nbE, 256, 0, stream>>>(dst, cnt, EE);
  k_scan1<<<nbScan, 1024, 0, stream>>>(cnt, rowptr, bsum, dinv, NN);
  k_scan2<<<1, 128, 0, stream>>>(bsum, nbScan);
  k_scan3<<<nbScan, 1024, 0, stream>>>(rowptr, bsum, NN, EE);
  k_binit<<<(NB + 255) / 256, 256, 0, stream>>>(rowptr, bcursor);
  k_bucketA<<<nbE, 256, 0, stream>>>(src, dst, bcursor, stage, EE);
  k_bucketB<<<NB, 256, 0, stream>>>(stage, rowptr, colbuf);

  int nbG1 = (NN + 63) / 64;
  k_gemm1<<<nbG1, 256, 0, stream>>>(x, W1, h1, NN);
  k_agg1<<<(NN + 3) / 4, 256, 0, stream>>>(h1, rowptr, colbuf, dinv, b1, agg1, NN);

  int nbG2 = (NN + 255) / 256;
  k_gemm2<<<nbG2, 256, 0, stream>>>((const __half*)agg1, W2, h2, NN);
  k_agg2<<<(NN * 8 + 255) / 256, 256, 0, stream>>>(h2, rowptr, colbuf, dinv, b2, out, NN);
}

// Round 6
// 260.125 us; speedup vs baseline: 1.7889x; 1.7889x over previous
//
#include <hip/hip_runtime.h>
#include <hip/hip_bf16.h>
#include <hip/hip_fp16.h>

#define NN 100000
#define EE 1600000
#define FF 128
#define HH 128
#define CC 8

#define CH 4096                        // edges per chunk (phase A block)
#define NBK ((NN + 511) / 512)         // 196 coarse buckets of 512 nodes
#define NCH ((EE + CH - 1) / CH)       // 391 chunks
#define HSZ (NBK * NCH)                // 76,636 histogram entries

typedef _Float16 half8 __attribute__((ext_vector_type(8)));
typedef float f32x4 __attribute__((ext_vector_type(4)));

// ---------------- degree ----------------
__global__ __launch_bounds__(256) void k_count(const int* __restrict__ dst,
                                               int* __restrict__ cnt, int e) {
  int i = blockIdx.x * 256 + threadIdx.x;
  if (i < e) atomicAdd(&cnt[dst[i]], 1);
}

// ---------------- generic exclusive scan (dinv fused when non-null) ---------
__global__ __launch_bounds__(1024) void k_scan1(const int* __restrict__ in,
                                                int* __restrict__ outp,
                                                int* __restrict__ bsum,
                                                float* __restrict__ dinv, int n) {
  __shared__ int sh[1024];
  int t = threadIdx.x;
  int i = blockIdx.x * 1024 + t;
  int v = (i < n) ? in[i] : 0;
  if (i < n && dinv) dinv[i] = rsqrtf((float)v + 1.0f);  // +1 self loop
  sh[t] = v;
  __syncthreads();
  for (int offs = 1; offs < 1024; offs <<= 1) {
    int add = (t >= offs) ? sh[t - offs] : 0;
    __syncthreads();
    sh[t] += add;
    __syncthreads();
  }
  if (i < n) outp[i] = sh[t] - v;  // exclusive
  if (t == 1023) bsum[blockIdx.x] = sh[1023];
}

__global__ __launch_bounds__(128) void k_scan2(int* __restrict__ bsum, int nb) {
  __shared__ int sh[128];
  int t = threadIdx.x;
  int v = (t < nb) ? bsum[t] : 0;
  sh[t] = v;
  __syncthreads();
  for (int offs = 1; offs < 128; offs <<= 1) {
    int add = (t >= offs) ? sh[t - offs] : 0;
    __syncthreads();
    sh[t] += add;
    __syncthreads();
  }
  if (t < nb) bsum[t] = sh[t] - v;  // exclusive
}

__global__ __launch_bounds__(1024) void k_scan3(int* __restrict__ outp,
                                                const int* __restrict__ bsum,
                                                int n, int e) {
  int i = blockIdx.x * 1024 + threadIdx.x;
  if (i < n) outp[i] += bsum[blockIdx.x];
  if (i == 0) outp[n] = e;  // sentinel
}

// ---------------- sort phase 1: per-chunk histogram over coarse buckets -----
__global__ __launch_bounds__(256) void k_histA(const int* __restrict__ dst,
                                               int* __restrict__ hist) {
  __shared__ int lh[NBK];
  int c = blockIdx.x, t = threadIdx.x;
  for (int b = t; b < NBK; b += 256) lh[b] = 0;
  __syncthreads();
  int e0 = c * CH, e1 = min(e0 + CH, EE);
  for (int j = e0 + t; j < e1; j += 256) atomicAdd(&lh[dst[j] >> 9], 1);
  __syncthreads();
  for (int b = t; b < NBK; b += 256) hist[b * NCH + c] = lh[b];
}

// ---------------- sort phase 2: scatter into bucketed stage -----------------
// stage[pos] = src | ((dst & 511) << 17)   (src < 2^17, 9-bit local dst)
__global__ __launch_bounds__(256) void k_scatA(const int* __restrict__ src,
                                               const int* __restrict__ dst,
                                               const int* __restrict__ hoff,
                                               unsigned int* __restrict__ stage) {
  __shared__ int lcur[NBK];
  int c = blockIdx.x, t = threadIdx.x;
  for (int b = t; b < NBK; b += 256) lcur[b] = hoff[b * NCH + c];
  __syncthreads();
  int e0 = c * CH, e1 = min(e0 + CH, EE);
  for (int j = e0 + t; j < e1; j += 256) {
    int d = dst[j];
    int pos = atomicAdd(&lcur[d >> 9], 1);
    stage[pos] = (unsigned int)src[j] | ((unsigned int)(d & 511) << 17);
  }
}

// ---------------- sort phase 3: one block per bucket -> final col -----------
__global__ __launch_bounds__(256) void k_bucketB(const unsigned int* __restrict__ stage,
                                                 const int* __restrict__ rowptr,
                                                 const int* __restrict__ hoff,
                                                 int* __restrict__ col) {
  __shared__ int lcur[512];
  int b = blockIdx.x, t = threadIdx.x;
  int n0 = b * 512;
  for (int i = t; i < 512; i += 256) {
    int node = n0 + i;
    lcur[i] = (node < NN) ? rowptr[node] : 0;
  }
  __syncthreads();
  int e0 = hoff[b * NCH];
  int e1 = hoff[(b + 1) * NCH];  // hoff[HSZ] = EE sentinel covers last bucket
  for (int j = e0 + t; j < e1; j += 256) {
    unsigned int v = stage[j];
    int pos = atomicAdd(&lcur[v >> 17], 1);
    col[pos] = (int)(v & 0x1FFFFu);
  }
}

// ---------------- GEMM1 (MFMA fp16): h = x @ W1, fp16 out -------------------
__global__ __launch_bounds__(256) void k_gemm1(const float* __restrict__ x,
                                               const float* __restrict__ W,
                                               __half* __restrict__ h, int n) {
  __shared__ _Float16 Wl[128 * 128];  // [c][k] swizzled
  int t = threadIdx.x;
  {
    int c = t & 127;
    int kg0 = t >> 7;  // 0..1
    for (int kg = kg0; kg < 16; kg += 2) {
      _Float16 tmp[8];
#pragma unroll
      for (int j = 0; j < 8; ++j)
        tmp[j] = (_Float16)W[(size_t)(kg * 8 + j) * 128 + c];
      int byteoff = (c * 256 + kg * 16) ^ ((c & 7) << 4);
      *(half8*)((char*)Wl + byteoff) = *(half8*)tmp;
    }
  }
  __syncthreads();

  int row0 = blockIdx.x * 64;
  int w = t >> 6, l = t & 63;
  int rw = w >> 1, cw = w & 1;
  int lr = l & 15, g = l >> 4;

  f32x4 acc[2][4];
#pragma unroll
  for (int ar = 0; ar < 2; ++ar)
#pragma unroll
    for (int bt = 0; bt < 4; ++bt)
#pragma unroll
      for (int r = 0; r < 4; ++r) acc[ar][bt][r] = 0.f;

  for (int kt = 0; kt < 4; ++kt) {
    half8 a[2];
#pragma unroll
    for (int ar = 0; ar < 2; ++ar) {
      int row = row0 + rw * 32 + ar * 16 + lr;
      if (row < n) {
        const float* p = &x[(size_t)row * 128 + kt * 32 + g * 8];
        float4 v0 = *(const float4*)p;
        float4 v1 = *(const float4*)(p + 4);
        a[ar][0] = (_Float16)v0.x; a[ar][1] = (_Float16)v0.y;
        a[ar][2] = (_Float16)v0.z; a[ar][3] = (_Float16)v0.w;
        a[ar][4] = (_Float16)v1.x; a[ar][5] = (_Float16)v1.y;
        a[ar][6] = (_Float16)v1.z; a[ar][7] = (_Float16)v1.w;
      } else {
#pragma unroll
        for (int j = 0; j < 8; ++j) a[ar][j] = (_Float16)0.f;
      }
    }
#pragma unroll
    for (int bt = 0; bt < 4; ++bt) {
      int c = cw * 64 + bt * 16 + lr;
      int byteoff = (c * 256 + kt * 64 + g * 16) ^ ((c & 7) << 4);
      half8 bb = *(const half8*)((const char*)Wl + byteoff);
      acc[0][bt] = __builtin_amdgcn_mfma_f32_16x16x32_f16(a[0], bb, acc[0][bt], 0, 0, 0);
      acc[1][bt] = __builtin_amdgcn_mfma_f32_16x16x32_f16(a[1], bb, acc[1][bt], 0, 0, 0);
    }
  }

#pragma unroll
  for (int ar = 0; ar < 2; ++ar)
#pragma unroll
    for (int bt = 0; bt < 4; ++bt)
#pragma unroll
      for (int r = 0; r < 4; ++r) {
        int row = row0 + rw * 32 + ar * 16 + g * 4 + r;
        int c = cw * 64 + bt * 16 + lr;
        if (row < n) h[(size_t)row * 128 + c] = __float2half(acc[ar][bt][r]);
      }
}

// ---------------- Agg1: out = relu(Anorm @ h + b1), wave per node, fp16 ----
__global__ __launch_bounds__(256) void k_agg1(const __half* __restrict__ h,
                                              const int* __restrict__ rowptr,
                                              const int* __restrict__ col,
                                              const float* __restrict__ dinv,
                                              const float* __restrict__ b1,
                                              __half2* __restrict__ out, int n) {
  int wid = threadIdx.x >> 6;
  int lane = threadIdx.x & 63;
  int node = blockIdx.x * 4 + wid;
  if (node >= n) return;
  float dn = dinv[node];
  const __half2* hp = (const __half2*)h;
  float2 acc = make_float2(0.f, 0.f);
  int e0 = rowptr[node], e1 = rowptr[node + 1];
  int e = e0;
  for (; e + 3 < e1; e += 4) {  // 4 gathers in flight
    int s0 = col[e], s1 = col[e + 1], s2 = col[e + 2], s3 = col[e + 3];
    float w0 = dinv[s0] * dn, w1 = dinv[s1] * dn;
    float w2 = dinv[s2] * dn, w3 = dinv[s3] * dn;
    float2 f0 = __half22float2(hp[(size_t)s0 * 64 + lane]);
    float2 f1 = __half22float2(hp[(size_t)s1 * 64 + lane]);
    float2 f2 = __half22float2(hp[(size_t)s2 * 64 + lane]);
    float2 f3 = __half22float2(hp[(size_t)s3 * 64 + lane]);
    acc.x = fmaf(w0, f0.x, acc.x); acc.y = fmaf(w0, f0.y, acc.y);
    acc.x = fmaf(w1, f1.x, acc.x); acc.y = fmaf(w1, f1.y, acc.y);
    acc.x = fmaf(w2, f2.x, acc.x); acc.y = fmaf(w2, f2.y, acc.y);
    acc.x = fmaf(w3, f3.x, acc.x); acc.y = fmaf(w3, f3.y, acc.y);
  }
  for (; e < e1; ++e) {
    int s = col[e];
    float w = dinv[s] * dn;
    float2 f = __half22float2(hp[(size_t)s * 64 + lane]);
    acc.x = fmaf(w, f.x, acc.x);
    acc.y = fmaf(w, f.y, acc.y);
  }
  {  // self loop
    float w = dn * dn;
    float2 f = __half22float2(hp[(size_t)node * 64 + lane]);
    acc.x = fmaf(w, f.x, acc.x);
    acc.y = fmaf(w, f.y, acc.y);
  }
  float2 bb = ((const float2*)b1)[lane];
  acc.x = fmaxf(acc.x + bb.x, 0.f);
  acc.y = fmaxf(acc.y + bb.y, 0.f);
  out[(size_t)node * 64 + lane] = __floats2half2_rn(acc.x, acc.y);
}

// ---------------- GEMM2: h2 = a @ W2 (fp16 in, fp16 out), thread per row ---
__global__ __launch_bounds__(256) void k_gemm2(const __half* __restrict__ a,
                                               const float* __restrict__ W2,
                                               __half* __restrict__ h2, int n) {
  int r = blockIdx.x * 256 + threadIdx.x;
  if (r >= n) return;
  float acc[8];
#pragma unroll
  for (int c = 0; c < 8; ++c) acc[c] = 0.f;
  const __half2* ap = (const __half2*)(a + (size_t)r * 128);
#pragma unroll 8
  for (int k2 = 0; k2 < 64; ++k2) {
    float2 v = __half22float2(ap[k2]);
    int k = k2 * 2;
#pragma unroll
    for (int c = 0; c < 8; ++c) {
      acc[c] = fmaf(v.x, W2[(k + 0) * 8 + c], acc[c]);
      acc[c] = fmaf(v.y, W2[(k + 1) * 8 + c], acc[c]);
    }
  }
  union { __half2 h2v[4]; uint2 u2[2]; } pk;
#pragma unroll
  for (int c = 0; c < 4; ++c)
    pk.h2v[c] = __floats2half2_rn(acc[2 * c], acc[2 * c + 1]);
  *(uint2*)&h2[(size_t)r * 8] = pk.u2[0];
  *(uint2*)&h2[(size_t)r * 8 + 4] = pk.u2[1];
}

// ---------------- Agg2: out = Anorm @ h2 + b2, 8 threads per node ----------
__global__ __launch_bounds__(256) void k_agg2(const __half* __restrict__ h2,
                                              const int* __restrict__ rowptr,
                                              const int* __restrict__ col,
                                              const float* __restrict__ dinv,
                                              const float* __restrict__ b2,
                                              float* __restrict__ out, int n) {
  int gthread = blockIdx.x * 256 + threadIdx.x;
  int node = gthread >> 3, f = gthread & 7;
  if (node >= n) return;
  float dn = dinv[node];
  float acc = 0.f;
  int e0 = rowptr[node], e1 = rowptr[node + 1];
  for (int e = e0; e < e1; ++e) {
    int s = col[e];
    acc = fmaf(dinv[s] * dn, __half2float(h2[(size_t)s * 8 + f]), acc);
  }
  acc = fmaf(dn * dn, __half2float(h2[(size_t)node * 8 + f]), acc);
  out[(size_t)node * 8 + f] = acc + b2[f];
}

extern "C" void kernel_launch(void* const* d_in, const int* in_sizes, int n_in,
                              void* d_out, int out_size, void* d_ws, size_t ws_size,
                              hipStream_t stream) {
  const float* x  = (const float*)d_in[0];
  const int* eidx = (const int*)d_in[1];
  const float* W1 = (const float*)d_in[2];
  const float* b1 = (const float*)d_in[3];
  const float* W2 = (const float*)d_in[4];
  const float* b2 = (const float*)d_in[5];
  float* out = (float*)d_out;
  const int* src = eidx;
  const int* dst = eidx + EE;

  char* ws = (char*)d_ws;
  size_t off = 0;
  auto alloc = [&](size_t bytes) -> char* {
    char* p = ws + off;
    off = (off + bytes + 255) & ~(size_t)255;
    return p;
  };

  int*          cnt    = (int*)         alloc((size_t)NN * 4);
  float*        dinv   = (float*)       alloc((size_t)NN * 4);
  int*          rowptr = (int*)         alloc((size_t)(NN + 1) * 4);
  int*          bsum   = (int*)         alloc(1024 * 4);
  int*          hist_g = (int*)         alloc((size_t)HSZ * 4);
  int*          hist_s = (int*)         alloc((size_t)(HSZ + 1) * 4);
  unsigned int* stage  = (unsigned int*)alloc((size_t)EE * 4);
  int*          colbuf = (int*)         alloc((size_t)EE * 4);
  __half*       h1     = (__half*)      alloc((size_t)NN * HH * 2);
  __half2*      agg1   = (__half2*)     alloc((size_t)NN * HH * 2);
  __half*       h2     = (__half*)h1;  // reuse: h1 dead after agg1

  hipMemsetAsync(cnt, 0, (size_t)NN * 4, stream);

  int nbE = (EE + 255) / 256;
  int nbScanN = (NN + 1023) / 1024;       // 98
  int nbScanH = (HSZ + 1023) / 1024;      // 75

  // degree + rowptr
  k_count<<<nbE, 256, 0, stream>>>(dst, cnt, EE);
  k_scan1<<<nbScanN, 1024, 0, stream>>>(cnt, rowptr, bsum, dinv, NN);
  k_scan2<<<1, 128, 0, stream>>>(bsum, nbScanN);
  k_scan3<<<nbScanN, 1024, 0, stream>>>(rowptr, bsum, NN, EE);

  // counting sort by dst (no global atomics)
  k_histA<<<NCH, 256, 0, stream>>>(dst, hist_g);
  k_scan1<<<nbScanH, 1024, 0, stream>>>(hist_g, hist_s, bsum, nullptr, HSZ);
  k_scan2<<<1, 128, 0, stream>>>(bsum, nbScanH);
  k_scan3<<<nbScanH, 1024, 0, stream>>>(hist_s, bsum, HSZ, EE);
  k_scatA<<<NCH, 256, 0, stream>>>(src, dst, hist_s, stage);
  k_bucketB<<<NBK, 256, 0, stream>>>(stage, rowptr, hist_s, colbuf);

  int nbG1 = (NN + 63) / 64;
  k_gemm1<<<nbG1, 256, 0, stream>>>(x, W1, h1, NN);
  k_agg1<<<(NN + 3) / 4, 256, 0, stream>>>(h1, rowptr, colbuf, dinv, b1, agg1, NN);

  int nbG2 = (NN + 255) / 256;
  k_gemm2<<<nbG2, 256, 0, stream>>>((const __half*)agg1, W2, h2, NN);
  k_agg2<<<(NN * 8 + 255) / 256, 256, 0, stream>>>(h2, rowptr, colbuf, dinv, b2, out, NN);
}

// Round 7
// 179.746 us; speedup vs baseline: 2.5888x; 1.4472x over previous
//
#include <hip/hip_runtime.h>
#include <hip/hip_bf16.h>
#include <hip/hip_fp16.h>

#define NN 100000
#define EE 1600000
#define FF 128
#define HH 128
#define CC 8

#define CH 4096                        // edges per chunk (phase A block)
#define NBK ((NN + 511) / 512)         // 196 coarse buckets of 512 nodes
#define NCH ((EE + CH - 1) / CH)       // 391 chunks
#define HSZ (NBK * NCH)                // 76,636 histogram entries

typedef _Float16 half8 __attribute__((ext_vector_type(8)));
typedef float f32x4 __attribute__((ext_vector_type(4)));

// ---------------- generic exclusive scan ----------------
__global__ __launch_bounds__(1024) void k_scan1(const int* __restrict__ in,
                                                int* __restrict__ outp,
                                                int* __restrict__ bsum, int n) {
  __shared__ int sh[1024];
  int t = threadIdx.x;
  int i = blockIdx.x * 1024 + t;
  int v = (i < n) ? in[i] : 0;
  sh[t] = v;
  __syncthreads();
  for (int offs = 1; offs < 1024; offs <<= 1) {
    int add = (t >= offs) ? sh[t - offs] : 0;
    __syncthreads();
    sh[t] += add;
    __syncthreads();
  }
  if (i < n) outp[i] = sh[t] - v;  // exclusive
  if (t == 1023) bsum[blockIdx.x] = sh[1023];
}

__global__ __launch_bounds__(128) void k_scan2(int* __restrict__ bsum, int nb) {
  __shared__ int sh[128];
  int t = threadIdx.x;
  int v = (t < nb) ? bsum[t] : 0;
  sh[t] = v;
  __syncthreads();
  for (int offs = 1; offs < 128; offs <<= 1) {
    int add = (t >= offs) ? sh[t - offs] : 0;
    __syncthreads();
    sh[t] += add;
    __syncthreads();
  }
  if (t < nb) bsum[t] = sh[t] - v;  // exclusive
}

__global__ __launch_bounds__(1024) void k_scan3(int* __restrict__ outp,
                                                const int* __restrict__ bsum,
                                                int n, int e) {
  int i = blockIdx.x * 1024 + threadIdx.x;
  if (i < n) outp[i] += bsum[blockIdx.x];
  if (i == 0) outp[n] = e;  // sentinel
}

// ---------------- sort phase 1: per-chunk histogram over coarse buckets -----
__global__ __launch_bounds__(256) void k_histA(const int* __restrict__ dst,
                                               int* __restrict__ hist) {
  __shared__ int lh[NBK];
  int c = blockIdx.x, t = threadIdx.x;
  for (int b = t; b < NBK; b += 256) lh[b] = 0;
  __syncthreads();
  int e0 = c * CH, e1 = min(e0 + CH, EE);
  for (int j = e0 + t; j < e1; j += 256) atomicAdd(&lh[dst[j] >> 9], 1);
  __syncthreads();
  for (int b = t; b < NBK; b += 256) hist[b * NCH + c] = lh[b];
}

// ---------------- sort phase 2: scatter into bucketed stage -----------------
// stage[pos] = src | ((dst & 511) << 17)   (src < 2^17, 9-bit local dst)
__global__ __launch_bounds__(256) void k_scatA(const int* __restrict__ src,
                                               const int* __restrict__ dst,
                                               const int* __restrict__ hoff,
                                               unsigned int* __restrict__ stage) {
  __shared__ int lcur[NBK];
  int c = blockIdx.x, t = threadIdx.x;
  for (int b = t; b < NBK; b += 256) lcur[b] = hoff[b * NCH + c];
  __syncthreads();
  int e0 = c * CH, e1 = min(e0 + CH, EE);
  for (int j = e0 + t; j < e1; j += 256) {
    int d = dst[j];
    int pos = atomicAdd(&lcur[d >> 9], 1);
    stage[pos] = (unsigned int)src[j] | ((unsigned int)(d & 511) << 17);
  }
}

// ---------------- sort phase 3: one block per bucket ------------------------
// Pass 1: LDS histogram of local dst -> LDS scan -> rowptr + dinv.
// Pass 2: scatter into final col with LDS cursors. No global atomics.
__global__ __launch_bounds__(256) void k_bucketB(const unsigned int* __restrict__ stage,
                                                 const int* __restrict__ hoff,
                                                 int* __restrict__ col,
                                                 int* __restrict__ rowptr,
                                                 float* __restrict__ dinv) {
  __shared__ int lcnt[512];
  __shared__ int lpart[256];
  int b = blockIdx.x, t = threadIdx.x;
  int n0 = b * 512;
  lcnt[t] = 0;
  lcnt[t + 256] = 0;
  __syncthreads();
  int e0 = hoff[b * NCH];
  int e1 = hoff[(b + 1) * NCH];  // hoff[HSZ] = EE sentinel covers last bucket
  for (int j = e0 + t; j < e1; j += 256)
    atomicAdd(&lcnt[stage[j] >> 17], 1);
  __syncthreads();
  int c0 = lcnt[2 * t], c1 = lcnt[2 * t + 1];
  lpart[t] = c0 + c1;
  __syncthreads();
  for (int offs = 1; offs < 256; offs <<= 1) {  // inclusive scan over pairs
    int add = (t >= offs) ? lpart[t - offs] : 0;
    __syncthreads();
    lpart[t] += add;
    __syncthreads();
  }
  int base0 = e0 + lpart[t] - (c0 + c1);  // exclusive
  int base1 = base0 + c0;
  int node0 = n0 + 2 * t, node1 = n0 + 2 * t + 1;
  if (node0 <= NN) rowptr[node0] = base0;  // node==NN writes sentinel EE
  if (node1 <= NN) rowptr[node1] = base1;
  if (node0 < NN) dinv[node0] = rsqrtf((float)c0 + 1.f);
  if (node1 < NN) dinv[node1] = rsqrtf((float)c1 + 1.f);
  lcnt[2 * t] = base0;  // reuse as cursors
  lcnt[2 * t + 1] = base1;
  __syncthreads();
  for (int j = e0 + t; j < e1; j += 256) {
    unsigned int v = stage[j];
    int pos = atomicAdd(&lcnt[v >> 17], 1);
    col[pos] = (int)(v & 0x1FFFFu);
  }
}

// ---------------- GEMM1 (MFMA fp16): h = x @ W1, fp16 out -------------------
__global__ __launch_bounds__(256) void k_gemm1(const float* __restrict__ x,
                                               const float* __restrict__ W,
                                               __half* __restrict__ h, int n) {
  __shared__ _Float16 Wl[128 * 128];  // [c][k] swizzled
  int t = threadIdx.x;
  {
    int c = t & 127;
    int kg0 = t >> 7;  // 0..1
    for (int kg = kg0; kg < 16; kg += 2) {
      _Float16 tmp[8];
#pragma unroll
      for (int j = 0; j < 8; ++j)
        tmp[j] = (_Float16)W[(size_t)(kg * 8 + j) * 128 + c];
      int byteoff = (c * 256 + kg * 16) ^ ((c & 7) << 4);
      *(half8*)((char*)Wl + byteoff) = *(half8*)tmp;
    }
  }
  __syncthreads();

  int row0 = blockIdx.x * 64;
  int w = t >> 6, l = t & 63;
  int rw = w >> 1, cw = w & 1;
  int lr = l & 15, g = l >> 4;

  f32x4 acc[2][4];
#pragma unroll
  for (int ar = 0; ar < 2; ++ar)
#pragma unroll
    for (int bt = 0; bt < 4; ++bt)
#pragma unroll
      for (int r = 0; r < 4; ++r) acc[ar][bt][r] = 0.f;

  for (int kt = 0; kt < 4; ++kt) {
    half8 a[2];
#pragma unroll
    for (int ar = 0; ar < 2; ++ar) {
      int row = row0 + rw * 32 + ar * 16 + lr;
      if (row < n) {
        const float* p = &x[(size_t)row * 128 + kt * 32 + g * 8];
        float4 v0 = *(const float4*)p;
        float4 v1 = *(const float4*)(p + 4);
        a[ar][0] = (_Float16)v0.x; a[ar][1] = (_Float16)v0.y;
        a[ar][2] = (_Float16)v0.z; a[ar][3] = (_Float16)v0.w;
        a[ar][4] = (_Float16)v1.x; a[ar][5] = (_Float16)v1.y;
        a[ar][6] = (_Float16)v1.z; a[ar][7] = (_Float16)v1.w;
      } else {
#pragma unroll
        for (int j = 0; j < 8; ++j) a[ar][j] = (_Float16)0.f;
      }
    }
#pragma unroll
    for (int bt = 0; bt < 4; ++bt) {
      int c = cw * 64 + bt * 16 + lr;
      int byteoff = (c * 256 + kt * 64 + g * 16) ^ ((c & 7) << 4);
      half8 bb = *(const half8*)((const char*)Wl + byteoff);
      acc[0][bt] = __builtin_amdgcn_mfma_f32_16x16x32_f16(a[0], bb, acc[0][bt], 0, 0, 0);
      acc[1][bt] = __builtin_amdgcn_mfma_f32_16x16x32_f16(a[1], bb, acc[1][bt], 0, 0, 0);
    }
  }

#pragma unroll
  for (int ar = 0; ar < 2; ++ar)
#pragma unroll
    for (int bt = 0; bt < 4; ++bt)
#pragma unroll
      for (int r = 0; r < 4; ++r) {
        int row = row0 + rw * 32 + ar * 16 + g * 4 + r;
        int c = cw * 64 + bt * 16 + lr;
        if (row < n) h[(size_t)row * 128 + c] = __float2half(acc[ar][bt][r]);
      }
}

// ---------------- Agg1: out = relu(Anorm @ h + b1), wave per node, fp16 ----
// 8 edges batched -> 8 h-row gathers + 8 dinv gathers in flight.
__global__ __launch_bounds__(256) void k_agg1(const __half* __restrict__ h,
                                              const int* __restrict__ rowptr,
                                              const int* __restrict__ col,
                                              const float* __restrict__ dinv,
                                              const float* __restrict__ b1,
                                              __half2* __restrict__ out, int n) {
  int wid = threadIdx.x >> 6;
  int lane = threadIdx.x & 63;
  int node = blockIdx.x * 4 + wid;
  if (node >= n) return;
  float dn = dinv[node];
  const __half2* hp = (const __half2*)h;
  float2 acc = make_float2(0.f, 0.f);
  int e0 = rowptr[node], e1 = rowptr[node + 1];
  int e = e0;
  for (; e + 7 < e1; e += 8) {
    int s[8];
#pragma unroll
    for (int u = 0; u < 8; ++u) s[u] = col[e + u];
    float w[8];
    __half2 f[8];
#pragma unroll
    for (int u = 0; u < 8; ++u) w[u] = dinv[s[u]];
#pragma unroll
    for (int u = 0; u < 8; ++u) f[u] = hp[(size_t)s[u] * 64 + lane];
#pragma unroll
    for (int u = 0; u < 8; ++u) {
      float2 ff = __half22float2(f[u]);
      float ww = w[u] * dn;
      acc.x = fmaf(ww, ff.x, acc.x);
      acc.y = fmaf(ww, ff.y, acc.y);
    }
  }
  for (; e + 1 < e1; e += 2) {
    int s0 = col[e], s1 = col[e + 1];
    float w0 = dinv[s0] * dn, w1 = dinv[s1] * dn;
    float2 f0 = __half22float2(hp[(size_t)s0 * 64 + lane]);
    float2 f1 = __half22float2(hp[(size_t)s1 * 64 + lane]);
    acc.x = fmaf(w0, f0.x, acc.x); acc.y = fmaf(w0, f0.y, acc.y);
    acc.x = fmaf(w1, f1.x, acc.x); acc.y = fmaf(w1, f1.y, acc.y);
  }
  if (e < e1) {
    int s = col[e];
    float w = dinv[s] * dn;
    float2 f = __half22float2(hp[(size_t)s * 64 + lane]);
    acc.x = fmaf(w, f.x, acc.x);
    acc.y = fmaf(w, f.y, acc.y);
  }
  {  // self loop
    float w = dn * dn;
    float2 f = __half22float2(hp[(size_t)node * 64 + lane]);
    acc.x = fmaf(w, f.x, acc.x);
    acc.y = fmaf(w, f.y, acc.y);
  }
  float2 bb = ((const float2*)b1)[lane];
  acc.x = fmaxf(acc.x + bb.x, 0.f);
  acc.y = fmaxf(acc.y + bb.y, 0.f);
  out[(size_t)node * 64 + lane] = __floats2half2_rn(acc.x, acc.y);
}

// ---------------- GEMM2: h2 = a @ W2 (fp16 in, fp16 out), thread per row ---
__global__ __launch_bounds__(256) void k_gemm2(const __half* __restrict__ a,
                                               const float* __restrict__ W2,
                                               __half* __restrict__ h2, int n) {
  int r = blockIdx.x * 256 + threadIdx.x;
  if (r >= n) return;
  float acc[8];
#pragma unroll
  for (int c = 0; c < 8; ++c) acc[c] = 0.f;
  const __half2* ap = (const __half2*)(a + (size_t)r * 128);
#pragma unroll 8
  for (int k2 = 0; k2 < 64; ++k2) {
    float2 v = __half22float2(ap[k2]);
    int k = k2 * 2;
#pragma unroll
    for (int c = 0; c < 8; ++c) {
      acc[c] = fmaf(v.x, W2[(k + 0) * 8 + c], acc[c]);
      acc[c] = fmaf(v.y, W2[(k + 1) * 8 + c], acc[c]);
    }
  }
  union { __half2 h2v[4]; uint2 u2[2]; } pk;
#pragma unroll
  for (int c = 0; c < 4; ++c)
    pk.h2v[c] = __floats2half2_rn(acc[2 * c], acc[2 * c + 1]);
  *(uint2*)&h2[(size_t)r * 8] = pk.u2[0];
  *(uint2*)&h2[(size_t)r * 8 + 4] = pk.u2[1];
}

// ---------------- Agg2: out = Anorm @ h2 + b2, 8 threads per node ----------
__global__ __launch_bounds__(256) void k_agg2(const __half* __restrict__ h2,
                                              const int* __restrict__ rowptr,
                                              const int* __restrict__ col,
                                              const float* __restrict__ dinv,
                                              const float* __restrict__ b2,
                                              float* __restrict__ out, int n) {
  int gthread = blockIdx.x * 256 + threadIdx.x;
  int node = gthread >> 3, f = gthread & 7;
  if (node >= n) return;
  float dn = dinv[node];
  float acc = 0.f;
  int e0 = rowptr[node], e1 = rowptr[node + 1];
  int e = e0;
  for (; e + 3 < e1; e += 4) {
    int s0 = col[e], s1 = col[e + 1], s2 = col[e + 2], s3 = col[e + 3];
    float w0 = dinv[s0], w1 = dinv[s1], w2 = dinv[s2], w3 = dinv[s3];
    float v0 = __half2float(h2[(size_t)s0 * 8 + f]);
    float v1 = __half2float(h2[(size_t)s1 * 8 + f]);
    float v2 = __half2float(h2[(size_t)s2 * 8 + f]);
    float v3 = __half2float(h2[(size_t)s3 * 8 + f]);
    acc = fmaf(w0 * dn, v0, acc);
    acc = fmaf(w1 * dn, v1, acc);
    acc = fmaf(w2 * dn, v2, acc);
    acc = fmaf(w3 * dn, v3, acc);
  }
  for (; e < e1; ++e) {
    int s = col[e];
    acc = fmaf(dinv[s] * dn, __half2float(h2[(size_t)s * 8 + f]), acc);
  }
  acc = fmaf(dn * dn, __half2float(h2[(size_t)node * 8 + f]), acc);
  out[(size_t)node * 8 + f] = acc + b2[f];
}

extern "C" void kernel_launch(void* const* d_in, const int* in_sizes, int n_in,
                              void* d_out, int out_size, void* d_ws, size_t ws_size,
                              hipStream_t stream) {
  const float* x  = (const float*)d_in[0];
  const int* eidx = (const int*)d_in[1];
  const float* W1 = (const float*)d_in[2];
  const float* b1 = (const float*)d_in[3];
  const float* W2 = (const float*)d_in[4];
  const float* b2 = (const float*)d_in[5];
  float* out = (float*)d_out;
  const int* src = eidx;
  const int* dst = eidx + EE;

  char* ws = (char*)d_ws;
  size_t off = 0;
  auto alloc = [&](size_t bytes) -> char* {
    char* p = ws + off;
    off = (off + bytes + 255) & ~(size_t)255;
    return p;
  };

  float*        dinv   = (float*)       alloc((size_t)NN * 4);
  int*          rowptr = (int*)         alloc((size_t)(NN + 1) * 4);
  int*          bsum   = (int*)         alloc(1024 * 4);
  int*          hist_g = (int*)         alloc((size_t)HSZ * 4);
  int*          hist_s = (int*)         alloc((size_t)(HSZ + 1) * 4);
  unsigned int* stage  = (unsigned int*)alloc((size_t)EE * 4);
  int*          colbuf = (int*)         alloc((size_t)EE * 4);
  __half*       h1     = (__half*)      alloc((size_t)NN * HH * 2);
  __half2*      agg1   = (__half2*)     alloc((size_t)NN * HH * 2);
  __half*       h2     = (__half*)h1;  // reuse: h1 dead after agg1

  int nbScanH = (HSZ + 1023) / 1024;  // 75

  // counting sort by dst (no global atomics); bucketB derives rowptr + dinv
  k_histA<<<NCH, 256, 0, stream>>>(dst, hist_g);
  k_scan1<<<nbScanH, 1024, 0, stream>>>(hist_g, hist_s, bsum, HSZ);
  k_scan2<<<1, 128, 0, stream>>>(bsum, nbScanH);
  k_scan3<<<nbScanH, 1024, 0, stream>>>(hist_s, bsum, HSZ, EE);
  k_scatA<<<NCH, 256, 0, stream>>>(src, dst, hist_s, stage);
  k_bucketB<<<NBK, 256, 0, stream>>>(stage, hist_s, colbuf, rowptr, dinv);

  int nbG1 = (NN + 63) / 64;
  k_gemm1<<<nbG1, 256, 0, stream>>>(x, W1, h1, NN);
  k_agg1<<<(NN + 3) / 4, 256, 0, stream>>>(h1, rowptr, colbuf, dinv, b1, agg1, NN);

  int nbG2 = (NN + 255) / 256;
  k_gemm2<<<nbG2, 256, 0, stream>>>((const __half*)agg1, W2, h2, NN);
  k_agg2<<<(NN * 8 + 255) / 256, 256, 0, stream>>>(h2, rowptr, colbuf, dinv, b2, out, NN);
}

// Round 8
// 176.310 us; speedup vs baseline: 2.6393x; 1.0195x over previous
//
#include <hip/hip_runtime.h>
#include <hip/hip_bf16.h>
#include <hip/hip_fp16.h>

#define NN 100000
#define EE 1600000
#define FF 128
#define HH 128
#define CC 8

#define CH 4096                        // edges per chunk (phase A block)
#define NBK ((NN + 255) / 256)         // 391 coarse buckets of 256 nodes
#define NCH ((EE + CH - 1) / CH)       // 391 chunks
#define HSZ (NBK * NCH)                // 152,881 histogram entries

typedef _Float16 half8 __attribute__((ext_vector_type(8)));
typedef float f32x4 __attribute__((ext_vector_type(4)));

// ---------------- generic exclusive scan ----------------
__global__ __launch_bounds__(1024) void k_scan1(const int* __restrict__ in,
                                                int* __restrict__ outp,
                                                int* __restrict__ bsum, int n) {
  __shared__ int sh[1024];
  int t = threadIdx.x;
  int i = blockIdx.x * 1024 + t;
  int v = (i < n) ? in[i] : 0;
  sh[t] = v;
  __syncthreads();
  for (int offs = 1; offs < 1024; offs <<= 1) {
    int add = (t >= offs) ? sh[t - offs] : 0;
    __syncthreads();
    sh[t] += add;
    __syncthreads();
  }
  if (i < n) outp[i] = sh[t] - v;  // exclusive
  if (t == 1023) bsum[blockIdx.x] = sh[1023];
}

__global__ __launch_bounds__(256) void k_scan2(int* __restrict__ bsum, int nb) {
  __shared__ int sh[256];
  int t = threadIdx.x;
  int v = (t < nb) ? bsum[t] : 0;
  sh[t] = v;
  __syncthreads();
  for (int offs = 1; offs < 256; offs <<= 1) {
    int add = (t >= offs) ? sh[t - offs] : 0;
    __syncthreads();
    sh[t] += add;
    __syncthreads();
  }
  if (t < nb) bsum[t] = sh[t] - v;  // exclusive
}

__global__ __launch_bounds__(1024) void k_scan3(int* __restrict__ outp,
                                                const int* __restrict__ bsum,
                                                int n, int e) {
  int i = blockIdx.x * 1024 + threadIdx.x;
  if (i < n) outp[i] += bsum[blockIdx.x];
  if (i == 0) outp[n] = e;  // sentinel
}

// ---------------- sort phase 1: per-chunk histogram over coarse buckets -----
__global__ __launch_bounds__(256) void k_histA(const int* __restrict__ dst,
                                               int* __restrict__ hist) {
  __shared__ int lh[NBK];
  int c = blockIdx.x, t = threadIdx.x;
  for (int b = t; b < NBK; b += 256) lh[b] = 0;
  __syncthreads();
  int e0 = c * CH, e1 = min(e0 + CH, EE);
  for (int j = e0 + t; j < e1; j += 256) atomicAdd(&lh[dst[j] >> 8], 1);
  __syncthreads();
  for (int b = t; b < NBK; b += 256) hist[b * NCH + c] = lh[b];
}

// ---------------- fused: scatA (blocks 0..NCH-1)  ||  gemm1 (rest) ----------
// scatA: stage[pos] = src | ((dst & 255) << 17)
// gemm1: h = x @ W1 via MFMA fp16, W1 transposed+swizzled in LDS.
__global__ __launch_bounds__(256) void k_scat_gemm1(
    const int* __restrict__ src, const int* __restrict__ dst,
    const int* __restrict__ hoff, unsigned int* __restrict__ stage,
    const float* __restrict__ x, const float* __restrict__ W,
    __half* __restrict__ h, int n) {
  __shared__ _Float16 Wl[128 * 128];  // 32 KB (scat uses first 1564 B as int*)
  int t = threadIdx.x;

  if (blockIdx.x < NCH) {  // ---- scatter into bucketed stage ----
    int* lcur = (int*)Wl;
    int c = blockIdx.x;
    for (int b = t; b < NBK; b += 256) lcur[b] = hoff[b * NCH + c];
    __syncthreads();
    int e0 = c * CH, e1 = min(e0 + CH, EE);
    for (int j = e0 + t; j < e1; j += 256) {
      int d = dst[j];
      int pos = atomicAdd(&lcur[d >> 8], 1);
      stage[pos] = (unsigned int)src[j] | ((unsigned int)(d & 255) << 17);
    }
    return;
  }

  // ---- gemm1 ----
  {
    int c = t & 127;
    int kg0 = t >> 7;  // 0..1
    for (int kg = kg0; kg < 16; kg += 2) {
      _Float16 tmp[8];
#pragma unroll
      for (int j = 0; j < 8; ++j)
        tmp[j] = (_Float16)W[(size_t)(kg * 8 + j) * 128 + c];
      int byteoff = (c * 256 + kg * 16) ^ ((c & 7) << 4);
      *(half8*)((char*)Wl + byteoff) = *(half8*)tmp;
    }
  }
  __syncthreads();

  int row0 = (blockIdx.x - NCH) * 64;
  int w = t >> 6, l = t & 63;
  int rw = w >> 1, cw = w & 1;
  int lr = l & 15, g = l >> 4;

  f32x4 acc[2][4];
#pragma unroll
  for (int ar = 0; ar < 2; ++ar)
#pragma unroll
    for (int bt = 0; bt < 4; ++bt)
#pragma unroll
      for (int r = 0; r < 4; ++r) acc[ar][bt][r] = 0.f;

  for (int kt = 0; kt < 4; ++kt) {
    half8 a[2];
#pragma unroll
    for (int ar = 0; ar < 2; ++ar) {
      int row = row0 + rw * 32 + ar * 16 + lr;
      if (row < n) {
        const float* p = &x[(size_t)row * 128 + kt * 32 + g * 8];
        float4 v0 = *(const float4*)p;
        float4 v1 = *(const float4*)(p + 4);
        a[ar][0] = (_Float16)v0.x; a[ar][1] = (_Float16)v0.y;
        a[ar][2] = (_Float16)v0.z; a[ar][3] = (_Float16)v0.w;
        a[ar][4] = (_Float16)v1.x; a[ar][5] = (_Float16)v1.y;
        a[ar][6] = (_Float16)v1.z; a[ar][7] = (_Float16)v1.w;
      } else {
#pragma unroll
        for (int j = 0; j < 8; ++j) a[ar][j] = (_Float16)0.f;
      }
    }
#pragma unroll
    for (int bt = 0; bt < 4; ++bt) {
      int c = cw * 64 + bt * 16 + lr;
      int byteoff = (c * 256 + kt * 64 + g * 16) ^ ((c & 7) << 4);
      half8 bb = *(const half8*)((const char*)Wl + byteoff);
      acc[0][bt] = __builtin_amdgcn_mfma_f32_16x16x32_f16(a[0], bb, acc[0][bt], 0, 0, 0);
      acc[1][bt] = __builtin_amdgcn_mfma_f32_16x16x32_f16(a[1], bb, acc[1][bt], 0, 0, 0);
    }
  }

#pragma unroll
  for (int ar = 0; ar < 2; ++ar)
#pragma unroll
    for (int bt = 0; bt < 4; ++bt)
#pragma unroll
      for (int r = 0; r < 4; ++r) {
        int row = row0 + rw * 32 + ar * 16 + g * 4 + r;
        int c = cw * 64 + bt * 16 + lr;
        if (row < n) h[(size_t)row * 128 + c] = __float2half(acc[ar][bt][r]);
      }
}

// ---------------- sort phase 3: one block per 256-node bucket ---------------
// Pass 1: LDS histogram -> LDS scan -> rowptr + dinv. Pass 2: scatter col.
__global__ __launch_bounds__(256) void k_bucketB(const unsigned int* __restrict__ stage,
                                                 const int* __restrict__ hoff,
                                                 int* __restrict__ col,
                                                 int* __restrict__ rowptr,
                                                 float* __restrict__ dinv) {
  __shared__ int lcnt[256];
  __shared__ int lpart[256];
  int b = blockIdx.x, t = threadIdx.x;
  int n0 = b * 256;
  lcnt[t] = 0;
  __syncthreads();
  int e0 = hoff[b * NCH];
  int e1 = hoff[(b + 1) * NCH];  // hoff[HSZ] = EE sentinel covers last bucket
  for (int j = e0 + t; j < e1; j += 256)
    atomicAdd(&lcnt[stage[j] >> 17], 1);
  __syncthreads();
  int c = lcnt[t];
  lpart[t] = c;
  __syncthreads();
  for (int offs = 1; offs < 256; offs <<= 1) {  // inclusive scan
    int add = (t >= offs) ? lpart[t - offs] : 0;
    __syncthreads();
    lpart[t] += add;
    __syncthreads();
  }
  int base = e0 + lpart[t] - c;  // exclusive
  int node = n0 + t;
  if (node <= NN) rowptr[node] = base;  // node==NN writes sentinel EE
  if (node < NN) dinv[node] = rsqrtf((float)c + 1.f);
  __syncthreads();
  lcnt[t] = base;  // reuse as cursors
  __syncthreads();
  for (int j = e0 + t; j < e1; j += 256) {
    unsigned int v = stage[j];
    int pos = atomicAdd(&lcnt[v >> 17], 1);
    col[pos] = (int)(v & 0x1FFFFu);
  }
}

// ---------------- Agg1 + GEMM2 fused: h2 = relu(Anorm@h + b1) @ W2 ---------
// Wave per node, lane owns features {2l, 2l+1}. After the fp32 row is built,
// dot with preloaded W2 rows and butterfly-reduce -> lane 0 stores 16B h2 row.
__global__ __launch_bounds__(256) void k_agg1f(const __half* __restrict__ h,
                                               const int* __restrict__ rowptr,
                                               const int* __restrict__ col,
                                               const float* __restrict__ dinv,
                                               const float* __restrict__ b1,
                                               const float* __restrict__ W2,
                                               __half* __restrict__ h2, int n) {
  int wid = threadIdx.x >> 6;
  int lane = threadIdx.x & 63;
  int node = blockIdx.x * 4 + wid;
  if (node >= n) return;
  // preload W2 rows 2*lane and 2*lane+1 (8 floats each)
  float4 wa0 = *(const float4*)&W2[(2 * lane) * 8];
  float4 wa1 = *(const float4*)&W2[(2 * lane) * 8 + 4];
  float4 wb0 = *(const float4*)&W2[(2 * lane + 1) * 8];
  float4 wb1 = *(const float4*)&W2[(2 * lane + 1) * 8 + 4];

  float dn = dinv[node];
  const __half2* hp = (const __half2*)h;
  float2 acc = make_float2(0.f, 0.f);
  int e0 = rowptr[node], e1 = rowptr[node + 1];
  int e = e0;
  for (; e + 7 < e1; e += 8) {
    int s[8];
#pragma unroll
    for (int u = 0; u < 8; ++u) s[u] = col[e + u];
    float w[8];
    __half2 f[8];
#pragma unroll
    for (int u = 0; u < 8; ++u) w[u] = dinv[s[u]];
#pragma unroll
    for (int u = 0; u < 8; ++u) f[u] = hp[(size_t)s[u] * 64 + lane];
#pragma unroll
    for (int u = 0; u < 8; ++u) {
      float2 ff = __half22float2(f[u]);
      float ww = w[u] * dn;
      acc.x = fmaf(ww, ff.x, acc.x);
      acc.y = fmaf(ww, ff.y, acc.y);
    }
  }
  for (; e + 1 < e1; e += 2) {
    int s0 = col[e], s1 = col[e + 1];
    float w0 = dinv[s0] * dn, w1 = dinv[s1] * dn;
    float2 f0 = __half22float2(hp[(size_t)s0 * 64 + lane]);
    float2 f1 = __half22float2(hp[(size_t)s1 * 64 + lane]);
    acc.x = fmaf(w0, f0.x, acc.x); acc.y = fmaf(w0, f0.y, acc.y);
    acc.x = fmaf(w1, f1.x, acc.x); acc.y = fmaf(w1, f1.y, acc.y);
  }
  if (e < e1) {
    int s = col[e];
    float w = dinv[s] * dn;
    float2 f = __half22float2(hp[(size_t)s * 64 + lane]);
    acc.x = fmaf(w, f.x, acc.x);
    acc.y = fmaf(w, f.y, acc.y);
  }
  {  // self loop
    float w = dn * dn;
    float2 f = __half22float2(hp[(size_t)node * 64 + lane]);
    acc.x = fmaf(w, f.x, acc.x);
    acc.y = fmaf(w, f.y, acc.y);
  }
  float2 bb = ((const float2*)b1)[lane];
  acc.x = fmaxf(acc.x + bb.x, 0.f);
  acc.y = fmaxf(acc.y + bb.y, 0.f);

  // fused gemm2: p[c] = acc.x*W2[2l][c] + acc.y*W2[2l+1][c], reduce over lanes
  float p0 = acc.x * wa0.x + acc.y * wb0.x;
  float p1 = acc.x * wa0.y + acc.y * wb0.y;
  float p2 = acc.x * wa0.z + acc.y * wb0.z;
  float p3 = acc.x * wa0.w + acc.y * wb0.w;
  float p4 = acc.x * wa1.x + acc.y * wb1.x;
  float p5 = acc.x * wa1.y + acc.y * wb1.y;
  float p6 = acc.x * wa1.z + acc.y * wb1.z;
  float p7 = acc.x * wa1.w + acc.y * wb1.w;
#pragma unroll
  for (int m = 1; m < 64; m <<= 1) {
    p0 += __shfl_xor(p0, m);
    p1 += __shfl_xor(p1, m);
    p2 += __shfl_xor(p2, m);
    p3 += __shfl_xor(p3, m);
    p4 += __shfl_xor(p4, m);
    p5 += __shfl_xor(p5, m);
    p6 += __shfl_xor(p6, m);
    p7 += __shfl_xor(p7, m);
  }
  if (lane == 0) {
    union { __half2 hh[4]; uint4 u; } pk;
    pk.hh[0] = __floats2half2_rn(p0, p1);
    pk.hh[1] = __floats2half2_rn(p2, p3);
    pk.hh[2] = __floats2half2_rn(p4, p5);
    pk.hh[3] = __floats2half2_rn(p6, p7);
    *(uint4*)&h2[(size_t)node * 8] = pk.u;
  }
}

// ---------------- Agg2: out = Anorm @ h2 + b2, 8 threads per node ----------
__global__ __launch_bounds__(256) void k_agg2(const __half* __restrict__ h2,
                                              const int* __restrict__ rowptr,
                                              const int* __restrict__ col,
                                              const float* __restrict__ dinv,
                                              const float* __restrict__ b2,
                                              float* __restrict__ out, int n) {
  int gthread = blockIdx.x * 256 + threadIdx.x;
  int node = gthread >> 3, f = gthread & 7;
  if (node >= n) return;
  float dn = dinv[node];
  float acc = 0.f;
  int e0 = rowptr[node], e1 = rowptr[node + 1];
  int e = e0;
  for (; e + 3 < e1; e += 4) {
    int s0 = col[e], s1 = col[e + 1], s2 = col[e + 2], s3 = col[e + 3];
    float w0 = dinv[s0], w1 = dinv[s1], w2 = dinv[s2], w3 = dinv[s3];
    float v0 = __half2float(h2[(size_t)s0 * 8 + f]);
    float v1 = __half2float(h2[(size_t)s1 * 8 + f]);
    float v2 = __half2float(h2[(size_t)s2 * 8 + f]);
    float v3 = __half2float(h2[(size_t)s3 * 8 + f]);
    acc = fmaf(w0 * dn, v0, acc);
    acc = fmaf(w1 * dn, v1, acc);
    acc = fmaf(w2 * dn, v2, acc);
    acc = fmaf(w3 * dn, v3, acc);
  }
  for (; e < e1; ++e) {
    int s = col[e];
    acc = fmaf(dinv[s] * dn, __half2float(h2[(size_t)s * 8 + f]), acc);
  }
  acc = fmaf(dn * dn, __half2float(h2[(size_t)node * 8 + f]), acc);
  out[(size_t)node * 8 + f] = acc + b2[f];
}

extern "C" void kernel_launch(void* const* d_in, const int* in_sizes, int n_in,
                              void* d_out, int out_size, void* d_ws, size_t ws_size,
                              hipStream_t stream) {
  const float* x  = (const float*)d_in[0];
  const int* eidx = (const int*)d_in[1];
  const float* W1 = (const float*)d_in[2];
  const float* b1 = (const float*)d_in[3];
  const float* W2 = (const float*)d_in[4];
  const float* b2 = (const float*)d_in[5];
  float* out = (float*)d_out;
  const int* src = eidx;
  const int* dst = eidx + EE;

  char* ws = (char*)d_ws;
  size_t off = 0;
  auto alloc = [&](size_t bytes) -> char* {
    char* p = ws + off;
    off = (off + bytes + 255) & ~(size_t)255;
    return p;
  };

  float*        dinv   = (float*)       alloc((size_t)NN * 4);
  int*          rowptr = (int*)         alloc((size_t)(NN + 1) * 4);
  int*          bsum   = (int*)         alloc(1024 * 4);
  int*          hist_g = (int*)         alloc((size_t)HSZ * 4);
  int*          hist_s = (int*)         alloc((size_t)(HSZ + 1) * 4);
  unsigned int* stage  = (unsigned int*)alloc((size_t)EE * 4);
  int*          colbuf = (int*)         alloc((size_t)EE * 4);
  __half*       h1     = (__half*)      alloc((size_t)NN * HH * 2);
  __half*       h2     = (__half*)      alloc((size_t)NN * CC * 2);

  int nbScanH = (HSZ + 1023) / 1024;  // 150

  // counting sort by dst (no global atomics); bucketB derives rowptr + dinv
  k_histA<<<NCH, 256, 0, stream>>>(dst, hist_g);
  k_scan1<<<nbScanH, 1024, 0, stream>>>(hist_g, hist_s, bsum, HSZ);
  k_scan2<<<1, 256, 0, stream>>>(bsum, nbScanH);
  k_scan3<<<nbScanH, 1024, 0, stream>>>(hist_s, bsum, HSZ, EE);

  // scatA || gemm1 fused (independent work, one dispatch)
  int nbG1 = (NN + 63) / 64;
  k_scat_gemm1<<<NCH + nbG1, 256, 0, stream>>>(src, dst, hist_s, stage,
                                               x, W1, h1, NN);
  k_bucketB<<<NBK, 256, 0, stream>>>(stage, hist_s, colbuf, rowptr, dinv);

  k_agg1f<<<(NN + 3) / 4, 256, 0, stream>>>(h1, rowptr, colbuf, dinv, b1, W2,
                                            h2, NN);
  k_agg2<<<(NN * 8 + 255) / 256, 256, 0, stream>>>(h2, rowptr, colbuf, dinv,
                                                   b2, out, NN);
}

// Round 9
// 165.895 us; speedup vs baseline: 2.8050x; 1.0628x over previous
//
#include <hip/hip_runtime.h>
#include <hip/hip_bf16.h>
#include <hip/hip_fp16.h>

#define NN 100000
#define EE 1600000
#define FF 128
#define HH 128
#define CC 8

#define CH 4096                        // edges per chunk (phase A block)
#define NBK ((NN + 255) / 256)         // 391 coarse buckets of 256 nodes
#define NCH ((EE + CH - 1) / CH)       // 391 chunks
#define HSZ (NBK * NCH)                // 152,881 histogram entries

typedef _Float16 half8 __attribute__((ext_vector_type(8)));
typedef float f32x4 __attribute__((ext_vector_type(4)));

// ---------------- generic exclusive scan ----------------
__global__ __launch_bounds__(1024) void k_scan1(const int* __restrict__ in,
                                                int* __restrict__ outp,
                                                int* __restrict__ bsum, int n) {
  __shared__ int sh[1024];
  int t = threadIdx.x;
  int i = blockIdx.x * 1024 + t;
  int v = (i < n) ? in[i] : 0;
  sh[t] = v;
  __syncthreads();
  for (int offs = 1; offs < 1024; offs <<= 1) {
    int add = (t >= offs) ? sh[t - offs] : 0;
    __syncthreads();
    sh[t] += add;
    __syncthreads();
  }
  if (i < n) outp[i] = sh[t] - v;  // exclusive
  if (t == 1023) bsum[blockIdx.x] = sh[1023];
}

__global__ __launch_bounds__(256) void k_scan2(int* __restrict__ bsum, int nb) {
  __shared__ int sh[256];
  int t = threadIdx.x;
  int v = (t < nb) ? bsum[t] : 0;
  sh[t] = v;
  __syncthreads();
  for (int offs = 1; offs < 256; offs <<= 1) {
    int add = (t >= offs) ? sh[t - offs] : 0;
    __syncthreads();
    sh[t] += add;
    __syncthreads();
  }
  if (t < nb) bsum[t] = sh[t] - v;  // exclusive
}

__global__ __launch_bounds__(1024) void k_scan3(int* __restrict__ outp,
                                                const int* __restrict__ bsum,
                                                int n, int e) {
  int i = blockIdx.x * 1024 + threadIdx.x;
  if (i < n) outp[i] += bsum[blockIdx.x];
  if (i == 0) outp[n] = e;  // sentinel
}

// ---------------- sort phase 1: per-chunk histogram over coarse buckets -----
__global__ __launch_bounds__(256) void k_histA(const int* __restrict__ dst,
                                               int* __restrict__ hist) {
  __shared__ int lh[NBK];
  int c = blockIdx.x, t = threadIdx.x;
  for (int b = t; b < NBK; b += 256) lh[b] = 0;
  __syncthreads();
  int e0 = c * CH, e1 = min(e0 + CH, EE);
  for (int j = e0 + t; j < e1; j += 256) atomicAdd(&lh[dst[j] >> 8], 1);
  __syncthreads();
  for (int b = t; b < NBK; b += 256) hist[b * NCH + c] = lh[b];
}

// ---------------- fused: scatA (blocks 0..NCH-1)  ||  gemm1 (rest) ----------
// scatA: stage[pos] = src | ((dst & 255) << 17)
// gemm1: h = x @ W1 via MFMA fp16, W1 transposed+swizzled in LDS.
__global__ __launch_bounds__(256) void k_scat_gemm1(
    const int* __restrict__ src, const int* __restrict__ dst,
    const int* __restrict__ hoff, unsigned int* __restrict__ stage,
    const float* __restrict__ x, const float* __restrict__ W,
    __half* __restrict__ h, int n) {
  __shared__ _Float16 Wl[128 * 128];  // 32 KB (scat uses first 1564 B as int*)
  int t = threadIdx.x;

  if (blockIdx.x < NCH) {  // ---- scatter into bucketed stage ----
    int* lcur = (int*)Wl;
    int c = blockIdx.x;
    for (int b = t; b < NBK; b += 256) lcur[b] = hoff[b * NCH + c];
    __syncthreads();
    int e0 = c * CH, e1 = min(e0 + CH, EE);
    for (int j = e0 + t; j < e1; j += 256) {
      int d = dst[j];
      int pos = atomicAdd(&lcur[d >> 8], 1);
      stage[pos] = (unsigned int)src[j] | ((unsigned int)(d & 255) << 17);
    }
    return;
  }

  // ---- gemm1 ----
  {
    int c = t & 127;
    int kg0 = t >> 7;  // 0..1
    for (int kg = kg0; kg < 16; kg += 2) {
      _Float16 tmp[8];
#pragma unroll
      for (int j = 0; j < 8; ++j)
        tmp[j] = (_Float16)W[(size_t)(kg * 8 + j) * 128 + c];
      int byteoff = (c * 256 + kg * 16) ^ ((c & 7) << 4);
      *(half8*)((char*)Wl + byteoff) = *(half8*)tmp;
    }
  }
  __syncthreads();

  int row0 = (blockIdx.x - NCH) * 64;
  int w = t >> 6, l = t & 63;
  int rw = w >> 1, cw = w & 1;
  int lr = l & 15, g = l >> 4;

  f32x4 acc[2][4];
#pragma unroll
  for (int ar = 0; ar < 2; ++ar)
#pragma unroll
    for (int bt = 0; bt < 4; ++bt)
#pragma unroll
      for (int r = 0; r < 4; ++r) acc[ar][bt][r] = 0.f;

  for (int kt = 0; kt < 4; ++kt) {
    half8 a[2];
#pragma unroll
    for (int ar = 0; ar < 2; ++ar) {
      int row = row0 + rw * 32 + ar * 16 + lr;
      if (row < n) {
        const float* p = &x[(size_t)row * 128 + kt * 32 + g * 8];
        float4 v0 = *(const float4*)p;
        float4 v1 = *(const float4*)(p + 4);
        a[ar][0] = (_Float16)v0.x; a[ar][1] = (_Float16)v0.y;
        a[ar][2] = (_Float16)v0.z; a[ar][3] = (_Float16)v0.w;
        a[ar][4] = (_Float16)v1.x; a[ar][5] = (_Float16)v1.y;
        a[ar][6] = (_Float16)v1.z; a[ar][7] = (_Float16)v1.w;
      } else {
#pragma unroll
        for (int j = 0; j < 8; ++j) a[ar][j] = (_Float16)0.f;
      }
    }
#pragma unroll
    for (int bt = 0; bt < 4; ++bt) {
      int c = cw * 64 + bt * 16 + lr;
      int byteoff = (c * 256 + kt * 64 + g * 16) ^ ((c & 7) << 4);
      half8 bb = *(const half8*)((const char*)Wl + byteoff);
      acc[0][bt] = __builtin_amdgcn_mfma_f32_16x16x32_f16(a[0], bb, acc[0][bt], 0, 0, 0);
      acc[1][bt] = __builtin_amdgcn_mfma_f32_16x16x32_f16(a[1], bb, acc[1][bt], 0, 0, 0);
    }
  }

#pragma unroll
  for (int ar = 0; ar < 2; ++ar)
#pragma unroll
    for (int bt = 0; bt < 4; ++bt)
#pragma unroll
      for (int r = 0; r < 4; ++r) {
        int row = row0 + rw * 32 + ar * 16 + g * 4 + r;
        int c = cw * 64 + bt * 16 + lr;
        if (row < n) h[(size_t)row * 128 + c] = __float2half(acc[ar][bt][r]);
      }
}

// ---------------- sort phase 3: one block per 256-node bucket ---------------
// Pass 1: LDS histogram -> LDS scan -> rowptr + dinv. Pass 2: scatter col.
__global__ __launch_bounds__(256) void k_bucketB(const unsigned int* __restrict__ stage,
                                                 const int* __restrict__ hoff,
                                                 int* __restrict__ col,
                                                 int* __restrict__ rowptr,
                                                 float* __restrict__ dinv) {
  __shared__ int lcnt[256];
  __shared__ int lpart[256];
  int b = blockIdx.x, t = threadIdx.x;
  int n0 = b * 256;
  lcnt[t] = 0;
  __syncthreads();
  int e0 = hoff[b * NCH];
  int e1 = hoff[(b + 1) * NCH];  // hoff[HSZ] = EE sentinel covers last bucket
  for (int j = e0 + t; j < e1; j += 256)
    atomicAdd(&lcnt[stage[j] >> 17], 1);
  __syncthreads();
  int c = lcnt[t];
  lpart[t] = c;
  __syncthreads();
  for (int offs = 1; offs < 256; offs <<= 1) {  // inclusive scan
    int add = (t >= offs) ? lpart[t - offs] : 0;
    __syncthreads();
    lpart[t] += add;
    __syncthreads();
  }
  int base = e0 + lpart[t] - c;  // exclusive
  int node = n0 + t;
  if (node <= NN) rowptr[node] = base;  // node==NN writes sentinel EE
  if (node < NN) dinv[node] = rsqrtf((float)c + 1.f);
  __syncthreads();
  lcnt[t] = base;  // reuse as cursors
  __syncthreads();
  for (int j = e0 + t; j < e1; j += 256) {
    unsigned int v = stage[j];
    int pos = atomicAdd(&lcnt[v >> 17], 1);
    col[pos] = (int)(v & 0x1FFFFu);
  }
}

// ---------------- Agg1: out = relu(Anorm @ h + b1), wave per node, fp16 ----
// 8 edges batched -> 8 h-row gathers + 8 dinv gathers in flight.
__global__ __launch_bounds__(256) void k_agg1(const __half* __restrict__ h,
                                              const int* __restrict__ rowptr,
                                              const int* __restrict__ col,
                                              const float* __restrict__ dinv,
                                              const float* __restrict__ b1,
                                              __half2* __restrict__ out, int n) {
  int wid = threadIdx.x >> 6;
  int lane = threadIdx.x & 63;
  int node = blockIdx.x * 4 + wid;
  if (node >= n) return;
  float dn = dinv[node];
  const __half2* hp = (const __half2*)h;
  float2 acc = make_float2(0.f, 0.f);
  int e0 = rowptr[node], e1 = rowptr[node + 1];
  int e = e0;
  for (; e + 7 < e1; e += 8) {
    int s[8];
#pragma unroll
    for (int u = 0; u < 8; ++u) s[u] = col[e + u];
    float w[8];
    __half2 f[8];
#pragma unroll
    for (int u = 0; u < 8; ++u) w[u] = dinv[s[u]];
#pragma unroll
    for (int u = 0; u < 8; ++u) f[u] = hp[(size_t)s[u] * 64 + lane];
#pragma unroll
    for (int u = 0; u < 8; ++u) {
      float2 ff = __half22float2(f[u]);
      float ww = w[u] * dn;
      acc.x = fmaf(ww, ff.x, acc.x);
      acc.y = fmaf(ww, ff.y, acc.y);
    }
  }
  for (; e + 1 < e1; e += 2) {
    int s0 = col[e], s1 = col[e + 1];
    float w0 = dinv[s0] * dn, w1 = dinv[s1] * dn;
    float2 f0 = __half22float2(hp[(size_t)s0 * 64 + lane]);
    float2 f1 = __half22float2(hp[(size_t)s1 * 64 + lane]);
    acc.x = fmaf(w0, f0.x, acc.x); acc.y = fmaf(w0, f0.y, acc.y);
    acc.x = fmaf(w1, f1.x, acc.x); acc.y = fmaf(w1, f1.y, acc.y);
  }
  if (e < e1) {
    int s = col[e];
    float w = dinv[s] * dn;
    float2 f = __half22float2(hp[(size_t)s * 64 + lane]);
    acc.x = fmaf(w, f.x, acc.x);
    acc.y = fmaf(w, f.y, acc.y);
  }
  {  // self loop
    float w = dn * dn;
    float2 f = __half22float2(hp[(size_t)node * 64 + lane]);
    acc.x = fmaf(w, f.x, acc.x);
    acc.y = fmaf(w, f.y, acc.y);
  }
  float2 bb = ((const float2*)b1)[lane];
  acc.x = fmaxf(acc.x + bb.x, 0.f);
  acc.y = fmaxf(acc.y + bb.y, 0.f);
  out[(size_t)node * 64 + lane] = __floats2half2_rn(acc.x, acc.y);
}

// ---------------- GEMM2: h2 = a @ W2 (fp16 in, fp16 out), thread per row ---
__global__ __launch_bounds__(256) void k_gemm2(const __half* __restrict__ a,
                                               const float* __restrict__ W2,
                                               __half* __restrict__ h2, int n) {
  int r = blockIdx.x * 256 + threadIdx.x;
  if (r >= n) return;
  float acc[8];
#pragma unroll
  for (int c = 0; c < 8; ++c) acc[c] = 0.f;
  const __half2* ap = (const __half2*)(a + (size_t)r * 128);
#pragma unroll 8
  for (int k2 = 0; k2 < 64; ++k2) {
    float2 v = __half22float2(ap[k2]);
    int k = k2 * 2;
#pragma unroll
    for (int c = 0; c < 8; ++c) {
      acc[c] = fmaf(v.x, W2[(k + 0) * 8 + c], acc[c]);
      acc[c] = fmaf(v.y, W2[(k + 1) * 8 + c], acc[c]);
    }
  }
  union { __half2 h2v[4]; uint4 u; } pk;
#pragma unroll
  for (int c = 0; c < 4; ++c)
    pk.h2v[c] = __floats2half2_rn(acc[2 * c], acc[2 * c + 1]);
  *(uint4*)&h2[(size_t)r * 8] = pk.u;
}

// ---------------- Agg2: out = Anorm @ h2 + b2, 8 threads per node ----------
__global__ __launch_bounds__(256) void k_agg2(const __half* __restrict__ h2,
                                              const int* __restrict__ rowptr,
                                              const int* __restrict__ col,
                                              const float* __restrict__ dinv,
                                              const float* __restrict__ b2,
                                              float* __restrict__ out, int n) {
  int gthread = blockIdx.x * 256 + threadIdx.x;
  int node = gthread >> 3, f = gthread & 7;
  if (node >= n) return;
  float dn = dinv[node];
  float acc = 0.f;
  int e0 = rowptr[node], e1 = rowptr[node + 1];
  int e = e0;
  for (; e + 3 < e1; e += 4) {
    int s0 = col[e], s1 = col[e + 1], s2 = col[e + 2], s3 = col[e + 3];
    float w0 = dinv[s0], w1 = dinv[s1], w2 = dinv[s2], w3 = dinv[s3];
    float v0 = __half2float(h2[(size_t)s0 * 8 + f]);
    float v1 = __half2float(h2[(size_t)s1 * 8 + f]);
    float v2 = __half2float(h2[(size_t)s2 * 8 + f]);
    float v3 = __half2float(h2[(size_t)s3 * 8 + f]);
    acc = fmaf(w0 * dn, v0, acc);
    acc = fmaf(w1 * dn, v1, acc);
    acc = fmaf(w2 * dn, v2, acc);
    acc = fmaf(w3 * dn, v3, acc);
  }
  for (; e < e1; ++e) {
    int s = col[e];
    acc = fmaf(dinv[s] * dn, __half2float(h2[(size_t)s * 8 + f]), acc);
  }
  acc = fmaf(dn * dn, __half2float(h2[(size_t)node * 8 + f]), acc);
  out[(size_t)node * 8 + f] = acc + b2[f];
}

extern "C" void kernel_launch(void* const* d_in, const int* in_sizes, int n_in,
                              void* d_out, int out_size, void* d_ws, size_t ws_size,
                              hipStream_t stream) {
  const float* x  = (const float*)d_in[0];
  const int* eidx = (const int*)d_in[1];
  const float* W1 = (const float*)d_in[2];
  const float* b1 = (const float*)d_in[3];
  const float* W2 = (const float*)d_in[4];
  const float* b2 = (const float*)d_in[5];
  float* out = (float*)d_out;
  const int* src = eidx;
  const int* dst = eidx + EE;

  char* ws = (char*)d_ws;
  size_t off = 0;
  auto alloc = [&](size_t bytes) -> char* {
    char* p = ws + off;
    off = (off + bytes + 255) & ~(size_t)255;
    return p;
  };

  float*        dinv   = (float*)       alloc((size_t)NN * 4);
  int*          rowptr = (int*)         alloc((size_t)(NN + 1) * 4);
  int*          bsum   = (int*)         alloc(1024 * 4);
  int*          hist_g = (int*)         alloc((size_t)HSZ * 4);
  int*          hist_s = (int*)         alloc((size_t)(HSZ + 1) * 4);
  unsigned int* stage  = (unsigned int*)alloc((size_t)EE * 4);
  int*          colbuf = (int*)         alloc((size_t)EE * 4);
  __half*       h1     = (__half*)      alloc((size_t)NN * HH * 2);
  __half2*      agg1   = (__half2*)     alloc((size_t)NN * HH * 2);
  __half*       h2     = (__half*)h1;  // reuse: h1 dead after agg1

  int nbScanH = (HSZ + 1023) / 1024;  // 150

  // counting sort by dst (no global atomics); bucketB derives rowptr + dinv
  k_histA<<<NCH, 256, 0, stream>>>(dst, hist_g);
  k_scan1<<<nbScanH, 1024, 0, stream>>>(hist_g, hist_s, bsum, HSZ);
  k_scan2<<<1, 256, 0, stream>>>(bsum, nbScanH);
  k_scan3<<<nbScanH, 1024, 0, stream>>>(hist_s, bsum, HSZ, EE);

  // scatA || gemm1 fused (independent work, one dispatch)
  int nbG1 = (NN + 63) / 64;
  k_scat_gemm1<<<NCH + nbG1, 256, 0, stream>>>(src, dst, hist_s, stage,
                                               x, W1, h1, NN);
  k_bucketB<<<NBK, 256, 0, stream>>>(stage, hist_s, colbuf, rowptr, dinv);

  k_agg1<<<(NN + 3) / 4, 256, 0, stream>>>(h1, rowptr, colbuf, dinv, b1, agg1, NN);
  k_gemm2<<<(NN + 255) / 256, 256, 0, stream>>>((const __half*)agg1, W2, h2, NN);
  k_agg2<<<(NN * 8 + 255) / 256, 256, 0, stream>>>(h2, rowptr, colbuf, dinv,
                                                   b2, out, NN);
}